// Round 3
// baseline (348.884 us; speedup 1.0000x reference)
//
#include <hip/hip_runtime.h>
#include <hip/hip_bf16.h>

#define N_NODES 100000
#define N_EDGES 600000
#define DFEAT 128
#define DOUT 256
#define BSTRIDE 32                      // ints per bucket row: [deg | 31 slots] = one 128B line
#define BCAP 31                         // Poisson(6) max deg ~25; P(overflow) ~ 7e-9
#define CVT_BLOCKS (N_NODES * DFEAT / 4 / 256)   // 12500
#define WT_BLOCKS 32                    // 8192 fragment entries / 256

typedef __attribute__((ext_vector_type(8))) short bf16x8;
typedef __attribute__((ext_vector_type(4))) float floatx4;

__device__ __forceinline__ short f32_to_bfbits(float f) {
    __hip_bfloat16 h = __float2bfloat16(f);
    return *reinterpret_cast<short*>(&h);
}
__device__ __forceinline__ float bfbits_to_f32(short s) {
    return __uint_as_float(((unsigned)(unsigned short)s) << 16);
}

// ---------------------------------------------------------------------------
// Prep: nf f32->bf16; W -> fragment-ordered bf16 wtf (entry e=(cb*8+kt)*64+lane,
// 16B = wt[n=cb*16+m][k=kt*32+q*8 .. +8), lane=q*16+m); zero bucket headers.
// ---------------------------------------------------------------------------
__global__ void __launch_bounds__(256)
prep_kernel(const float* __restrict__ nf, __hip_bfloat16* __restrict__ nfb,
            const float* __restrict__ w, short* __restrict__ wtf,
            int* __restrict__ ebuf) {
    int b = blockIdx.x;
    int tid = threadIdx.x;
    if (b < CVT_BLOCKS) {
        int i = b * 256 + tid;                 // exactly covers 3.2M float4
        float4 v = reinterpret_cast<const float4*>(nf)[i];
        short4 o;
        o.x = f32_to_bfbits(v.x); o.y = f32_to_bfbits(v.y);
        o.z = f32_to_bfbits(v.z); o.w = f32_to_bfbits(v.w);
        reinterpret_cast<short4*>(nfb)[i] = o;
        if (i < N_NODES) ebuf[i * BSTRIDE] = 0;   // zero degree headers
    } else {
        int e = (b - CVT_BLOCKS) * 256 + tid;  // 0..8191 fragment entries
        int lane = e & 63;
        int kt = (e >> 6) & 7;
        int cb = e >> 9;
        int m = lane & 15;
        int q = lane >> 4;
        int n = cb * 16 + m;
        int k0 = kt * 32 + q * 8;
        bf16x8 t;
        #pragma unroll
        for (int j = 0; j < 8; ++j)
            t[j] = f32_to_bfbits(w[(size_t)(k0 + j) * DOUT + n]);
        reinterpret_cast<bf16x8*>(wtf)[e] = t;
    }
}

// ---------------------------------------------------------------------------
// Bucket fill: 4 edges/thread via int4. Header int doubles as degree counter.
// ---------------------------------------------------------------------------
__global__ void __launch_bounds__(256)
fill_bucket_kernel(const int* __restrict__ ei, int* __restrict__ ebuf) {
    int t = blockIdx.x * blockDim.x + threadIdx.x;
    int e0 = t * 4;
    if (e0 >= N_EDGES) return;                 // N_EDGES % 4 == 0
    int4 r4 = *reinterpret_cast<const int4*>(ei + e0);
    int4 c4 = *reinterpret_cast<const int4*>(ei + N_EDGES + e0);
    #define PROC(rr, cc)                                                        \
        if ((rr) != (cc)) {                                                     \
            int pos = atomicAdd(&ebuf[(rr) * BSTRIDE], 1);                      \
            if (pos < BCAP) ebuf[(rr) * BSTRIDE + 1 + pos] = (cc);              \
        }
    PROC(r4.x, c4.x) PROC(r4.y, c4.y) PROC(r4.z, c4.z) PROC(r4.w, c4.w)
    #undef PROC
}

// ---------------------------------------------------------------------------
// Aggregation: gather + mean -> agg bf16[N][128]. Latency-bound phase gets its
// own kernel: tiny register state, no LDS -> 6-8 waves/SIMD of TLP.
// Wave = 16 rows; lane (q,m) owns row m's bytes [kt*32 + q*8).
// ---------------------------------------------------------------------------
__global__ void __launch_bounds__(256, 6)
agg_kernel(const __hip_bfloat16* __restrict__ nfb,
           const int* __restrict__ ebuf,
           __hip_bfloat16* __restrict__ agg) {
    int tid  = threadIdx.x;
    int wave = tid >> 6;
    int lane = tid & 63;
    int m    = lane & 15;
    int q    = lane >> 4;

    int row = blockIdx.x * 64 + wave * 16 + m;
    int arow = row < N_NODES ? row : N_NODES - 1;   // clamp loads; store guarded
    const __hip_bfloat16* nbase = nfb + q * 8;

    const int* bp = ebuf + (size_t)arow * BSTRIDE;
    int4 h0 = *reinterpret_cast<const int4*>(bp);      // deg, n0, n1, n2
    int4 h1 = *reinterpret_cast<const int4*>(bp + 4);  // n3..n6
    int4 h2 = *reinterpret_cast<const int4*>(bp + 8);  // n7..n10
    int d = h0.x < BCAP ? h0.x : BCAP;

    float facc[4][8];
    #pragma unroll
    for (int kt = 0; kt < 4; ++kt)
        #pragma unroll
        for (int i = 0; i < 8; ++i) facc[kt][i] = 0.f;

    int idx[11] = {h0.y, h0.z, h0.w, h1.x, h1.y, h1.z, h1.w,
                   h2.x, h2.y, h2.z, h2.w};
    #pragma unroll
    for (int j = 0; j < 11; ++j) {
        int   cj = j < d ? idx[j] : arow;   // clamped: valid addr (L1-hot), weight 0
        float wj = j < d ? 1.0f : 0.0f;
        const __hip_bfloat16* p = nbase + (size_t)cj * DFEAT;
        #pragma unroll
        for (int kt = 0; kt < 4; ++kt) {
            bf16x8 v = *reinterpret_cast<const bf16x8*>(p + kt * 32);
            #pragma unroll
            for (int i = 0; i < 8; ++i)
                facc[kt][i] = fmaf(bfbits_to_f32(v[i]), wj, facc[kt][i]);
        }
    }
    if (d > 11) {                           // rare tail: P(d>11) ~ 2% / row
        for (int j = 11; j < d; ++j) {
            int cj = bp[1 + j];
            const __hip_bfloat16* p = nbase + (size_t)cj * DFEAT;
            #pragma unroll
            for (int kt = 0; kt < 4; ++kt) {
                bf16x8 v = *reinterpret_cast<const bf16x8*>(p + kt * 32);
                #pragma unroll
                for (int i = 0; i < 8; ++i)
                    facc[kt][i] += bfbits_to_f32(v[i]);
            }
        }
    }

    if (row >= N_NODES) return;
    float invc = 1.0f / fmaxf((float)d, 1.0f);
    __hip_bfloat16* orow = agg + (size_t)arow * DFEAT + q * 8;
    #pragma unroll
    for (int kt = 0; kt < 4; ++kt) {
        bf16x8 a;
        #pragma unroll
        for (int i = 0; i < 8; ++i) a[i] = f32_to_bfbits(facc[kt][i] * invc);
        *reinterpret_cast<bf16x8*>(orow + kt * 32) = a;
    }
}

// ---------------------------------------------------------------------------
// GEMM + bias + L2-norm. 512 threads = 8 waves; wave owns ONE 16-row tile.
// Live regs ~115 (acc 64 + afrag 32 + addr) -> genuinely fits the 128 budget
// of (512,4): 2 blocks/CU (LDS 64KB x2), 4 waves/SIMD, no spill.
// Two-pass GEMM over cb halves; wt staged via global_load_lds width=16.
// ---------------------------------------------------------------------------
__device__ __forceinline__ void stage_half(const int4* __restrict__ wtf4, int half,
                                           int4* sh4, int wave, int lane) {
    const int4* src = wtf4 + half * 4096;
    #pragma unroll
    for (int it = 0; it < 8; ++it) {
        int idx = it * 512 + wave * 64;        // int4 units, wave-uniform dest
        __builtin_amdgcn_global_load_lds(
            (const __attribute__((address_space(1))) void*)(src + idx + lane),
            (__attribute__((address_space(3))) void*)(sh4 + idx),
            16, 0, 0);
    }
}

__global__ void __launch_bounds__(512, 4)
gemm_kernel(const __hip_bfloat16* __restrict__ nfb,
            const __hip_bfloat16* __restrict__ agg,
            const short* __restrict__ wtf,
            const float* __restrict__ bias,
            float* __restrict__ out) {
    __shared__ int4 sh4[4096];             // 64 KB: half of wt in fragment order
    const short* shs = reinterpret_cast<const short*>(sh4);
    const int4* wtf4 = reinterpret_cast<const int4*>(wtf);

    int tid  = threadIdx.x;
    int wave = tid >> 6;
    int lane = tid & 63;
    int m    = lane & 15;
    int q    = lane >> 4;

    stage_half(wtf4, 0, sh4, wave, lane);  // async; drained by first barrier

    int rowBase = blockIdx.x * 128 + wave * 16;
    int arow = rowBase + m;
    if (arow >= N_NODES) arow = N_NODES - 1;   // clamp loads; stores guarded

    bf16x8 afrag[8];
    const __hip_bfloat16* grow = agg + (size_t)arow * DFEAT + q * 8;
    const __hip_bfloat16* srow = nfb + (size_t)arow * DFEAT + q * 8;
    #pragma unroll
    for (int kt = 0; kt < 4; ++kt) {
        afrag[kt]     = *reinterpret_cast<const bf16x8*>(grow + kt * 32);
        afrag[4 + kt] = *reinterpret_cast<const bf16x8*>(srow + kt * 32);
    }

    __syncthreads();   // half0 staged (vmcnt drained), afrag loads done

    floatx4 acc[16];
    #pragma unroll
    for (int cb = 0; cb < 16; ++cb) acc[cb] = (floatx4){0.f, 0.f, 0.f, 0.f};

    // ---- pass 1: cb 0..7 ----
    #pragma unroll
    for (int kt = 0; kt < 8; ++kt) {
        bf16x8 a = afrag[kt];
        #pragma unroll
        for (int cbl = 0; cbl < 8; ++cbl) {
            bf16x8 b = *reinterpret_cast<const bf16x8*>(
                shs + ((size_t)(cbl * 8 + kt) * 64 + lane) * 8);
            acc[cbl] = __builtin_amdgcn_mfma_f32_16x16x32_bf16(a, b, acc[cbl], 0, 0, 0);
        }
    }

    __syncthreads();                       // all pass-1 ds_reads complete
    stage_half(wtf4, 1, sh4, wave, lane);
    __syncthreads();                       // half1 staged (vmcnt drained)

    // ---- pass 2: cb 8..15 ----
    #pragma unroll
    for (int kt = 0; kt < 8; ++kt) {
        bf16x8 a = afrag[kt];
        #pragma unroll
        for (int cbl = 0; cbl < 8; ++cbl) {
            bf16x8 b = *reinterpret_cast<const bf16x8*>(
                shs + ((size_t)(cbl * 8 + kt) * 64 + lane) * 8);
            acc[8 + cbl] = __builtin_amdgcn_mfma_f32_16x16x32_bf16(a, b, acc[8 + cbl], 0, 0, 0);
        }
    }

    // ---- epilogue: bias, row L2-norm, store ----
    float ss[4] = {0.f, 0.f, 0.f, 0.f};
    #pragma unroll
    for (int cb = 0; cb < 16; ++cb) {
        float bv = bias[cb * 16 + m];
        #pragma unroll
        for (int rg = 0; rg < 4; ++rg) {
            float v = acc[cb][rg] + bv;
            acc[cb][rg] = v;
            ss[rg] += v * v;
        }
    }
    #pragma unroll
    for (int s = 1; s < 16; s <<= 1) {
        #pragma unroll
        for (int rg = 0; rg < 4; ++rg) ss[rg] += __shfl_xor(ss[rg], s, 64);
    }
    #pragma unroll
    for (int rg = 0; rg < 4; ++rg) {
        int r = rowBase + q * 4 + rg;
        if (r >= N_NODES) continue;
        float inv = 1.0f / fmaxf(sqrtf(ss[rg]), 1e-12f);
        size_t base = (size_t)r * DOUT + m;
        #pragma unroll
        for (int cb = 0; cb < 16; ++cb) out[base + cb * 16] = acc[cb][rg] * inv;
    }
}

extern "C" void kernel_launch(void* const* d_in, const int* in_sizes, int n_in,
                              void* d_out, int out_size, void* d_ws, size_t ws_size,
                              hipStream_t stream) {
    const float* nf   = (const float*)d_in[0];
    const int*   ei   = (const int*)d_in[1];
    const float* w    = (const float*)d_in[2];
    const float* bias = (const float*)d_in[3];
    float* out = (float*)d_out;

    // Workspace (~64.1 MB):
    //   nfb  : 100000*128 bf16      (25.6 MB)
    //   agg  : 100000*128 bf16      (25.6 MB)  -- mean-aggregated features
    //   ebuf : 100000*32 int        (12.8 MB)  -- [deg | 31 neighbors] = 1 line/row
    //   wtf  : 8192*16B             (128 KB)   -- fragment-ordered wt
    __hip_bfloat16* nfb = (__hip_bfloat16*)d_ws;
    __hip_bfloat16* agg = nfb + (size_t)N_NODES * DFEAT;
    int* ebuf = (int*)(agg + (size_t)N_NODES * DFEAT);
    short* wtf = (short*)(ebuf + (size_t)N_NODES * BSTRIDE);

    prep_kernel<<<CVT_BLOCKS + WT_BLOCKS, 256, 0, stream>>>(nf, nfb, w, wtf, ebuf);

    int eb = (N_EDGES / 4 + 255) / 256;   // 586
    fill_bucket_kernel<<<eb, 256, 0, stream>>>(ei, ebuf);

    int ab = (N_NODES + 63) / 64;         // 1563
    agg_kernel<<<ab, 256, 0, stream>>>(nfb, ebuf, agg);

    int gb = (N_NODES + 127) / 128;       // 782
    gemm_kernel<<<gb, 512, 0, stream>>>(nfb, agg, wtf, bias, out);
}

// Round 4
// 238.264 us; speedup vs baseline: 1.4643x; 1.4643x over previous
//
#include <hip/hip_runtime.h>
#include <hip/hip_bf16.h>

#define N_NODES 100000
#define N_EDGES 600000
#define DFEAT 128
#define DOUT 256
#define BSTRIDE 32                      // ints per bucket row: [deg | 31 slots] = one 128B line
#define BCAP 31                         // Poisson(6) max deg ~25; P(overflow) ~ 7e-9
#define CVT_BLOCKS (N_NODES * DFEAT / 4 / 256)   // 12500
#define WT_BLOCKS 32                    // 8192 fragment entries / 256

typedef __attribute__((ext_vector_type(8))) short bf16x8;
typedef __attribute__((ext_vector_type(4))) float floatx4;

__device__ __forceinline__ short f32_to_bfbits(float f) {
    __hip_bfloat16 h = __float2bfloat16(f);
    return *reinterpret_cast<short*>(&h);
}
__device__ __forceinline__ float bfbits_to_f32(short s) {
    return __uint_as_float(((unsigned)(unsigned short)s) << 16);
}

// ---------------------------------------------------------------------------
// Prep: nf f32->bf16; W -> fragment-ordered bf16 wtf (entry e=(cb*8+kt)*64+lane,
// 16B = wt[n=cb*16+m][k=kt*32+q*8 .. +8), lane=q*16+m); zero bucket headers.
// ---------------------------------------------------------------------------
__global__ void __launch_bounds__(256)
prep_kernel(const float* __restrict__ nf, __hip_bfloat16* __restrict__ nfb,
            const float* __restrict__ w, short* __restrict__ wtf,
            int* __restrict__ ebuf) {
    int b = blockIdx.x;
    int tid = threadIdx.x;
    if (b < CVT_BLOCKS) {
        int i = b * 256 + tid;                 // exactly covers 3.2M float4
        float4 v = reinterpret_cast<const float4*>(nf)[i];
        short4 o;
        o.x = f32_to_bfbits(v.x); o.y = f32_to_bfbits(v.y);
        o.z = f32_to_bfbits(v.z); o.w = f32_to_bfbits(v.w);
        reinterpret_cast<short4*>(nfb)[i] = o;
        if (i < N_NODES) ebuf[i * BSTRIDE] = 0;   // zero degree headers
    } else {
        int e = (b - CVT_BLOCKS) * 256 + tid;  // 0..8191 fragment entries
        int lane = e & 63;
        int kt = (e >> 6) & 7;
        int cb = e >> 9;
        int m = lane & 15;
        int q = lane >> 4;
        int n = cb * 16 + m;
        int k0 = kt * 32 + q * 8;
        bf16x8 t;
        #pragma unroll
        for (int j = 0; j < 8; ++j)
            t[j] = f32_to_bfbits(w[(size_t)(k0 + j) * DOUT + n]);
        reinterpret_cast<bf16x8*>(wtf)[e] = t;
    }
}

// ---------------------------------------------------------------------------
// Bucket fill: 4 edges/thread via int4. Header int doubles as degree counter.
// ---------------------------------------------------------------------------
__global__ void __launch_bounds__(256)
fill_bucket_kernel(const int* __restrict__ ei, int* __restrict__ ebuf) {
    int t = blockIdx.x * blockDim.x + threadIdx.x;
    int e0 = t * 4;
    if (e0 >= N_EDGES) return;                 // N_EDGES % 4 == 0
    int4 r4 = *reinterpret_cast<const int4*>(ei + e0);
    int4 c4 = *reinterpret_cast<const int4*>(ei + N_EDGES + e0);
    #define PROC(rr, cc)                                                        \
        if ((rr) != (cc)) {                                                     \
            int pos = atomicAdd(&ebuf[(rr) * BSTRIDE], 1);                      \
            if (pos < BCAP) ebuf[(rr) * BSTRIDE + 1 + pos] = (cc);              \
        }
    PROC(r4.x, c4.x) PROC(r4.y, c4.y) PROC(r4.z, c4.z) PROC(r4.w, c4.w)
    #undef PROC
}

// ---------------------------------------------------------------------------
// Aggregation: gather + mean -> agg bf16[N][128].
// 8 lanes per row, 16 features per lane: facc = 16 regs, total live ~48 ->
// compiler fits <=64 VGPR naturally (8 waves/SIMD, no launch_bounds forcing,
// NO SPILL -- round 2/3 both regressed by capping regs below live state).
// 32 rows/block, 3125 blocks = exactly N_NODES.
// ---------------------------------------------------------------------------
__global__ void __launch_bounds__(256)
agg_kernel(const __hip_bfloat16* __restrict__ nfb,
           const int* __restrict__ ebuf,
           __hip_bfloat16* __restrict__ agg) {
    int gt  = blockIdx.x * 256 + threadIdx.x;
    int row = gt >> 3;                  // 8 lanes per row; always < N_NODES
    int h   = gt & 7;                   // features [h*16, h*16+16)

    const int* bp = ebuf + (size_t)row * BSTRIDE;
    int4 h0 = *reinterpret_cast<const int4*>(bp);      // deg, n0, n1, n2
    int4 h1 = *reinterpret_cast<const int4*>(bp + 4);  // n3..n6
    int4 h2 = *reinterpret_cast<const int4*>(bp + 8);  // n7..n10
    int d = h0.x < BCAP ? h0.x : BCAP;

    const __hip_bfloat16* nbase = nfb + h * 16;

    float facc[2][8];
    #pragma unroll
    for (int half = 0; half < 2; ++half)
        #pragma unroll
        for (int i = 0; i < 8; ++i) facc[half][i] = 0.f;

    int idx[11] = {h0.y, h0.z, h0.w, h1.x, h1.y, h1.z, h1.w,
                   h2.x, h2.y, h2.z, h2.w};
    #pragma unroll
    for (int j = 0; j < 11; ++j) {
        int   cj = j < d ? idx[j] : row;    // clamped: valid addr (L1-hot), weight 0
        float wj = j < d ? 1.0f : 0.0f;
        const __hip_bfloat16* p = nbase + (size_t)cj * DFEAT;
        bf16x8 v0 = *reinterpret_cast<const bf16x8*>(p);
        bf16x8 v1 = *reinterpret_cast<const bf16x8*>(p + 8);
        #pragma unroll
        for (int i = 0; i < 8; ++i) {
            facc[0][i] = fmaf(bfbits_to_f32(v0[i]), wj, facc[0][i]);
            facc[1][i] = fmaf(bfbits_to_f32(v1[i]), wj, facc[1][i]);
        }
    }
    if (d > 11) {                           // rare tail: P(d>11) ~ 2% / row
        for (int j = 11; j < d; ++j) {
            int cj = bp[1 + j];
            const __hip_bfloat16* p = nbase + (size_t)cj * DFEAT;
            bf16x8 v0 = *reinterpret_cast<const bf16x8*>(p);
            bf16x8 v1 = *reinterpret_cast<const bf16x8*>(p + 8);
            #pragma unroll
            for (int i = 0; i < 8; ++i) {
                facc[0][i] += bfbits_to_f32(v0[i]);
                facc[1][i] += bfbits_to_f32(v1[i]);
            }
        }
    }

    float invc = 1.0f / fmaxf((float)d, 1.0f);
    __hip_bfloat16* orow = agg + (size_t)row * DFEAT + h * 16;
    #pragma unroll
    for (int half = 0; half < 2; ++half) {
        bf16x8 a;
        #pragma unroll
        for (int i = 0; i < 8; ++i) a[i] = f32_to_bfbits(facc[half][i] * invc);
        *reinterpret_cast<bf16x8*>(orow + half * 8) = a;
    }
}

// ---------------------------------------------------------------------------
// GEMM + bias + L2-norm. 512 threads = 8 waves; wave owns ONE 16-row tile.
// Live regs ~115 (acc 64 + afrag 32 + addr) fits the 128 budget of (512,4):
// 2 blocks/CU (LDS 64KB x2), 4 waves/SIMD.
// Two-pass GEMM over cb halves; wt staged via global_load_lds width=16.
// ---------------------------------------------------------------------------
__device__ __forceinline__ void stage_half(const int4* __restrict__ wtf4, int half,
                                           int4* sh4, int wave, int lane) {
    const int4* src = wtf4 + half * 4096;
    #pragma unroll
    for (int it = 0; it < 8; ++it) {
        int idx = it * 512 + wave * 64;        // int4 units, wave-uniform dest
        __builtin_amdgcn_global_load_lds(
            (const __attribute__((address_space(1))) void*)(src + idx + lane),
            (__attribute__((address_space(3))) void*)(sh4 + idx),
            16, 0, 0);
    }
}

__global__ void __launch_bounds__(512, 4)
gemm_kernel(const __hip_bfloat16* __restrict__ nfb,
            const __hip_bfloat16* __restrict__ agg,
            const short* __restrict__ wtf,
            const float* __restrict__ bias,
            float* __restrict__ out) {
    __shared__ int4 sh4[4096];             // 64 KB: half of wt in fragment order
    const short* shs = reinterpret_cast<const short*>(sh4);
    const int4* wtf4 = reinterpret_cast<const int4*>(wtf);

    int tid  = threadIdx.x;
    int wave = tid >> 6;
    int lane = tid & 63;
    int m    = lane & 15;
    int q    = lane >> 4;

    stage_half(wtf4, 0, sh4, wave, lane);  // async; drained by first barrier

    int rowBase = blockIdx.x * 128 + wave * 16;
    int arow = rowBase + m;
    if (arow >= N_NODES) arow = N_NODES - 1;   // clamp loads; stores guarded

    bf16x8 afrag[8];
    const __hip_bfloat16* grow = agg + (size_t)arow * DFEAT + q * 8;
    const __hip_bfloat16* srow = nfb + (size_t)arow * DFEAT + q * 8;
    #pragma unroll
    for (int kt = 0; kt < 4; ++kt) {
        afrag[kt]     = *reinterpret_cast<const bf16x8*>(grow + kt * 32);
        afrag[4 + kt] = *reinterpret_cast<const bf16x8*>(srow + kt * 32);
    }

    __syncthreads();   // half0 staged (vmcnt drained), afrag loads done

    floatx4 acc[16];
    #pragma unroll
    for (int cb = 0; cb < 16; ++cb) acc[cb] = (floatx4){0.f, 0.f, 0.f, 0.f};

    // ---- pass 1: cb 0..7 ----
    #pragma unroll
    for (int kt = 0; kt < 8; ++kt) {
        bf16x8 a = afrag[kt];
        #pragma unroll
        for (int cbl = 0; cbl < 8; ++cbl) {
            bf16x8 b = *reinterpret_cast<const bf16x8*>(
                shs + ((size_t)(cbl * 8 + kt) * 64 + lane) * 8);
            acc[cbl] = __builtin_amdgcn_mfma_f32_16x16x32_bf16(a, b, acc[cbl], 0, 0, 0);
        }
    }

    __syncthreads();                       // all pass-1 ds_reads complete
    stage_half(wtf4, 1, sh4, wave, lane);
    __syncthreads();                       // half1 staged (vmcnt drained)

    // ---- pass 2: cb 8..15 ----
    #pragma unroll
    for (int kt = 0; kt < 8; ++kt) {
        bf16x8 a = afrag[kt];
        #pragma unroll
        for (int cbl = 0; cbl < 8; ++cbl) {
            bf16x8 b = *reinterpret_cast<const bf16x8*>(
                shs + ((size_t)(cbl * 8 + kt) * 64 + lane) * 8);
            acc[8 + cbl] = __builtin_amdgcn_mfma_f32_16x16x32_bf16(a, b, acc[8 + cbl], 0, 0, 0);
        }
    }

    // ---- epilogue: bias, row L2-norm, store ----
    float ss[4] = {0.f, 0.f, 0.f, 0.f};
    #pragma unroll
    for (int cb = 0; cb < 16; ++cb) {
        float bv = bias[cb * 16 + m];
        #pragma unroll
        for (int rg = 0; rg < 4; ++rg) {
            float v = acc[cb][rg] + bv;
            acc[cb][rg] = v;
            ss[rg] += v * v;
        }
    }
    #pragma unroll
    for (int s = 1; s < 16; s <<= 1) {
        #pragma unroll
        for (int rg = 0; rg < 4; ++rg) ss[rg] += __shfl_xor(ss[rg], s, 64);
    }
    #pragma unroll
    for (int rg = 0; rg < 4; ++rg) {
        int r = rowBase + q * 4 + rg;
        if (r >= N_NODES) continue;
        float inv = 1.0f / fmaxf(sqrtf(ss[rg]), 1e-12f);
        size_t base = (size_t)r * DOUT + m;
        #pragma unroll
        for (int cb = 0; cb < 16; ++cb) out[base + cb * 16] = acc[cb][rg] * inv;
    }
}

extern "C" void kernel_launch(void* const* d_in, const int* in_sizes, int n_in,
                              void* d_out, int out_size, void* d_ws, size_t ws_size,
                              hipStream_t stream) {
    const float* nf   = (const float*)d_in[0];
    const int*   ei   = (const int*)d_in[1];
    const float* w    = (const float*)d_in[2];
    const float* bias = (const float*)d_in[3];
    float* out = (float*)d_out;

    // Workspace (~64.1 MB):
    //   nfb  : 100000*128 bf16      (25.6 MB)
    //   agg  : 100000*128 bf16      (25.6 MB)  -- mean-aggregated features
    //   ebuf : 100000*32 int        (12.8 MB)  -- [deg | 31 neighbors] = 1 line/row
    //   wtf  : 8192*16B             (128 KB)   -- fragment-ordered wt
    __hip_bfloat16* nfb = (__hip_bfloat16*)d_ws;
    __hip_bfloat16* agg = nfb + (size_t)N_NODES * DFEAT;
    int* ebuf = (int*)(agg + (size_t)N_NODES * DFEAT);
    short* wtf = (short*)(ebuf + (size_t)N_NODES * BSTRIDE);

    prep_kernel<<<CVT_BLOCKS + WT_BLOCKS, 256, 0, stream>>>(nf, nfb, w, wtf, ebuf);

    int eb = (N_EDGES / 4 + 255) / 256;   // 586
    fill_bucket_kernel<<<eb, 256, 0, stream>>>(ei, ebuf);

    int ab = N_NODES / 32;                // 3125, exact
    agg_kernel<<<ab, 256, 0, stream>>>(nfb, ebuf, agg);

    int gb = (N_NODES + 127) / 128;       // 782
    gemm_kernel<<<gb, 512, 0, stream>>>(nfb, agg, wtf, bias, out);
}